// Round 4
// baseline (5815.335 us; speedup 1.0000x reference)
//
#include <hip/hip_runtime.h>
#include <stdint.h>

// FPS: B=8, C=3, N=131072, S=2048.
// 16 blocks x 256 threads per batch (128 blocks, cooperative).
// batch = blockIdx % 8 -> co-XCD placement heuristic (L2 locality only).
// Each thread: 32 points in registers (coords + running min-dist).
// Per round: update + tree argmax -> DPP wave max (u64 packed) -> parity LDS
// exchange (ONE barrier) -> leader posts slot (agent scope) -> pipelined poll
// of 16 slots -> 4-step DPP max -> far (scalar) -> s_load coords.
// Packed: (valbits<<32) | ((0x1FFFF-idx)<<12) | tag; u64 max ==
// (value desc, index asc) lexicographic == jnp.argmax first-occurrence.

#define BATCHES 8
#define NPTS    131072
#define KBLK    16
#define TPB     256
#define NWAVE   (TPB / 64)
#define CHUNK   (NPTS / KBLK)   // 8192
#define PPT     (CHUNK / TPB)   // 32

// u64 (value,invidx,tag) max-combine with DPP-moved candidate; invalid source
// lanes keep their own value (old = own) so the combine is a no-op there.
#define DPP_COMBINE(ctrl)                                                      \
  {                                                                            \
    unsigned nlo = (unsigned)__builtin_amdgcn_update_dpp(                      \
        (int)lo, (int)lo, (ctrl), 0xF, 0xF, false);                            \
    unsigned nhi = (unsigned)__builtin_amdgcn_update_dpp(                      \
        (int)hi, (int)hi, (ctrl), 0xF, 0xF, false);                            \
    unsigned long long oo = ((unsigned long long)nhi << 32) | nlo;             \
    unsigned long long cc = ((unsigned long long)hi << 32) | lo;               \
    if (oo > cc) { lo = nlo; hi = nhi; }                                       \
  }

// Full-wave (64 lane) max; result broadcast via readlane(63) -> uniform.
__device__ __forceinline__ unsigned long long wave_max64(unsigned long long p) {
    unsigned lo = (unsigned)p, hi = (unsigned)(p >> 32);
    DPP_COMBINE(0x111);  // row_shr:1
    DPP_COMBINE(0x112);  // row_shr:2
    DPP_COMBINE(0x114);  // row_shr:4
    DPP_COMBINE(0x118);  // row_shr:8
    DPP_COMBINE(0x142);  // row_bcast:15
    DPP_COMBINE(0x143);  // row_bcast:31
    unsigned rlo = (unsigned)__builtin_amdgcn_readlane((int)lo, 63);
    unsigned rhi = (unsigned)__builtin_amdgcn_readlane((int)hi, 63);
    return ((unsigned long long)rhi << 32) | rlo;
}

// Max over 16 values replicated every 16 lanes; result uniform.
__device__ __forceinline__ unsigned long long row16_max64(unsigned long long p) {
    unsigned lo = (unsigned)p, hi = (unsigned)(p >> 32);
    DPP_COMBINE(0x111);
    DPP_COMBINE(0x112);
    DPP_COMBINE(0x114);
    DPP_COMBINE(0x118);
    unsigned rlo = (unsigned)__builtin_amdgcn_readlane((int)lo, 15);
    unsigned rhi = (unsigned)__builtin_amdgcn_readlane((int)hi, 15);
    return ((unsigned long long)rhi << 32) | rlo;
}

__global__ __launch_bounds__(TPB) void fps_kernel(
    const float* __restrict__ pts, float* __restrict__ out,
    unsigned long long* __restrict__ part, int S)
{
    const int gb   = blockIdx.x;
    const int b    = gb & (BATCHES - 1);   // batch (co-XCD)
    const int blk  = gb >> 3;              // 0..15 within batch
    const int tid  = threadIdx.x;
    const int lane = tid & 63;
    const int wv   = tid >> 6;

    const float* X = pts + (size_t)(b * 3 + 0) * NPTS;
    const float* Y = pts + (size_t)(b * 3 + 1) * NPTS;
    const float* Z = pts + (size_t)(b * 3 + 2) * NPTS;
    float* outb = out + (size_t)b * 3 * S;

    const int base = blk * CHUNK + tid;    // owned: base + k*TPB, k<PPT

    float px[PPT], py[PPT], pz[PPT], md[PPT];
#pragma unroll
    for (int k = 0; k < PPT; ++k) {
        int gi = base + k * TPB;
        px[k] = X[gi]; py[k] = Y[gi]; pz[k] = Z[gi];
        md[k] = 1e10f;
    }

    __shared__ unsigned long long s_part[2][NWAVE];

    unsigned long long* const slotsA = part + (size_t)b * KBLK;
    unsigned long long* const slotsB = part + (size_t)(BATCHES + b) * KBLK;
    const int myslot = lane & (KBLK - 1);

    // Round 0 selection is index 0 (reference).
    float cx = X[0], cy = Y[0], cz = Z[0];
    if (blk == 0 && tid == 0) {
        outb[0]              = cx;
        outb[(size_t)S]      = cy;
        outb[(size_t)2 * S]  = cz;
    }

    for (int t = 0; t < S - 1; ++t) {
        // --- update min-dist; tree argmax (left-priority == first match) ---
        float tv[PPT];
        int   tk[PPT];
#pragma unroll
        for (int k = 0; k < PPT; ++k) {
            float dx = __fsub_rn(px[k], cx);
            float dy = __fsub_rn(py[k], cy);
            float dz = __fsub_rn(pz[k], cz);
            // numpy/jax order: (dx*dx + dy*dy) + dz*dz, no FMA contraction
            float d  = __fadd_rn(__fadd_rn(__fmul_rn(dx, dx), __fmul_rn(dy, dy)),
                                 __fmul_rn(dz, dz));
            float m  = fminf(md[k], d);
            md[k] = m;
            tv[k] = m;
            tk[k] = k;
        }
#pragma unroll
        for (int s = 1; s < PPT; s <<= 1) {
#pragma unroll
            for (int k = 0; k + s < PPT; k += 2 * s) {
                if (tv[k + s] > tv[k]) { tv[k] = tv[k + s]; tk[k] = tk[k + s]; }
            }
        }
        const float bv = tv[0];
        const int   bi = base + tk[0] * TPB;

        const unsigned long long tag = (unsigned long long)(t + 1); // 1..2047
        unsigned long long p =
            ((unsigned long long)__float_as_uint(bv) << 32) |
            ((unsigned long long)(unsigned)(0x1FFFF - bi) << 12) | tag;

        // --- wave max (DPP), uniform result ---
        p = wave_max64(p);

        // --- cross-wave exchange: parity slot -> ONE barrier per round ---
        if (lane == 0) s_part[t & 1][wv] = p;
        __syncthreads();
        unsigned long long bp = s_part[t & 1][0];
#pragma unroll
        for (int w = 1; w < NWAVE; ++w) {
            unsigned long long o = s_part[t & 1][w];
            if (o > bp) bp = o;
        }

        // --- post block partial ---
        unsigned long long* slots = (t & 1) ? slotsB : slotsA;
        if (tid == 0)
            __hip_atomic_store(&slots[blk], bp,
                               __ATOMIC_RELAXED, __HIP_MEMORY_SCOPE_AGENT);

        // --- pipelined poll: 2 outstanding loads on the 2 slot lines ---
        unsigned long long got;
        unsigned long long g0 = __hip_atomic_load(&slots[myslot],
                                   __ATOMIC_RELAXED, __HIP_MEMORY_SCOPE_AGENT);
        for (;;) {
            unsigned long long g1 = __hip_atomic_load(&slots[myslot],
                                       __ATOMIC_RELAXED, __HIP_MEMORY_SCOPE_AGENT);
            if (__all((int)((g0 & 0xFFFull) == tag))) { got = g0; break; }
            g0 = __hip_atomic_load(&slots[myslot],
                                   __ATOMIC_RELAXED, __HIP_MEMORY_SCOPE_AGENT);
            if (__all((int)((g1 & 0xFFFull) == tag))) { got = g1; break; }
        }

        // --- max over the 16 partials (DPP, 4 steps), uniform ---
        got = row16_max64(got);
        const int far = 0x1FFFF - (int)((got >> 12) & 0x1FFFF);

        // --- next center (uniform -> scalar loads, L2-hot) + emit output ---
        cx = X[far]; cy = Y[far]; cz = Z[far];
        if (blk == 0 && tid == 0) {
            outb[(size_t)(t + 1)]         = cx;
            outb[(size_t)S + (t + 1)]     = cy;
            outb[(size_t)2 * S + (t + 1)] = cz;
        }
    }
}

extern "C" void kernel_launch(void* const* d_in, const int* in_sizes, int n_in,
                              void* d_out, int out_size, void* d_ws, size_t ws_size,
                              hipStream_t stream) {
    const float* pts = (const float*)d_in[0];
    float* out = (float*)d_out;
    unsigned long long* part = (unsigned long long*)d_ws;
    int S = out_size / (BATCHES * 3);   // 2048

    // Reset sync slots every replay (captured in the graph).
    hipMemsetAsync(d_ws, 0,
                   (size_t)2 * BATCHES * KBLK * sizeof(unsigned long long),
                   stream);

    void* args[] = { (void*)&pts, (void*)&out, (void*)&part, (void*)&S };
    hipLaunchCooperativeKernel((const void*)fps_kernel,
                               dim3(BATCHES * KBLK), dim3(TPB),
                               args, 0, stream);
}

// Round 5
// 5807.280 us; speedup vs baseline: 1.0014x; 1.0014x over previous
//
#include <hip/hip_runtime.h>
#include <stdint.h>

// FPS: B=8, C=3, N=131072, S=2048.
// Batch-PAIRED latency hiding: 64 blocks x 512 threads (cooperative).
// Pair p (0..3) serves batches A=p and B=p+4 with 16 blocks each.
// Per iteration (one round for BOTH batches):
//   updA -> waveRedA -> LDS redA -> postA      (tid0 posts while others run B)
//   updB -> waveRedB -> LDS redB -> postB
//   pollA (posted ~1300cy ago -> ready) -> farA -> coordsA/emitA
//   pollB (posted ~600cy ago, ages during A's tail) -> farB -> coordsB/emitB
// Cross-block L3 round-trip is hidden behind the other batch's compute.
// Packed: (valbits<<32) | ((0x1FFFF-idx)<<12) | tag ; u64 max ==
// (value desc, index asc) == jnp.argmax first-occurrence. Exact __f*_rn
// arithmetic, (dx*dx+dy*dy)+dz*dz order — trajectory bitwise-identical
// to the reference (absmax 0 in rounds 1-4).

#define BATCHES 8
#define NPTS    131072
#define KBLK    16                 // blocks per batch
#define TPB     512
#define NWAVE   (TPB / 64)
#define CHUNK   (NPTS / KBLK)      // 8192
#define PPT     (CHUNK / TPB)      // 16 points per thread per batch
#define NPAIR   4

// update + wave shfl butterfly + LDS exchange + leader post (one batch phase)
#define PHASE(px, py, pz, md, cx, cy, cz, sp, slots)                           \
  do {                                                                         \
    float bv = -1.0f;                                                          \
    int   bi = 0x7FFFFFFF;                                                     \
    _Pragma("unroll")                                                          \
    for (int k = 0; k < PPT; ++k) {                                            \
      float dx = __fsub_rn(px[k], cx);                                         \
      float dy = __fsub_rn(py[k], cy);                                         \
      float dz = __fsub_rn(pz[k], cz);                                         \
      /* numpy/jax order: (dx*dx + dy*dy) + dz*dz, no FMA contraction */       \
      float d  = __fadd_rn(__fadd_rn(__fmul_rn(dx, dx), __fmul_rn(dy, dy)),    \
                           __fmul_rn(dz, dz));                                 \
      float m  = fminf(md[k], d);                                              \
      md[k] = m;                                                               \
      if (m > bv) { bv = m; bi = base + k * TPB; }                             \
    }                                                                          \
    unsigned long long pk =                                                    \
        ((unsigned long long)__float_as_uint(bv) << 32) |                      \
        ((unsigned long long)(unsigned)(0x1FFFF - bi) << 12) | tag;            \
    _Pragma("unroll")                                                          \
    for (int off = 32; off >= 1; off >>= 1) {                                  \
      unsigned long long o = __shfl_xor(pk, off);                              \
      if (o > pk) pk = o;                                                      \
    }                                                                          \
    if (lane == 0) sp[wv] = pk;                                                \
    __syncthreads();                                                           \
    if (tid == 0) {                                                            \
      unsigned long long bp = sp[0];                                           \
      _Pragma("unroll")                                                        \
      for (int w = 1; w < NWAVE; ++w) {                                        \
        unsigned long long o = sp[w];                                          \
        if (o > bp) bp = o;                                                    \
      }                                                                        \
      __hip_atomic_store(&slots[blk], bp, __ATOMIC_RELAXED,                    \
                         __HIP_MEMORY_SCOPE_AGENT);                            \
    }                                                                          \
  } while (0)

// poll 16 slots (lane&15) until all tagged, butterfly to uniform max
#define POLL(slots, outvar)                                                    \
  do {                                                                         \
    unsigned long long g;                                                      \
    for (;;) {                                                                 \
      g = __hip_atomic_load(&slots[myslot], __ATOMIC_RELAXED,                  \
                            __HIP_MEMORY_SCOPE_AGENT);                         \
      if (__all((int)((g & 0xFFFull) == tag))) break;                          \
    }                                                                          \
    _Pragma("unroll")                                                          \
    for (int off = 8; off >= 1; off >>= 1) {                                   \
      unsigned long long o = __shfl_xor(g, off);                               \
      if (o > g) g = o;                                                        \
    }                                                                          \
    outvar = g;                                                                \
  } while (0)

__global__ __launch_bounds__(TPB, 2) void fps_kernel(
    const float* __restrict__ pts, float* __restrict__ out,
    unsigned long long* __restrict__ part, int S)
{
    const int gb   = blockIdx.x;           // 0..63
    const int pr   = gb & (NPAIR - 1);     // pair 0..3
    const int blk  = gb >> 2;              // 0..15 within pair group
    const int bA   = pr;                   // batch A
    const int bB   = pr + 4;               // batch B
    const int tid  = threadIdx.x;
    const int lane = tid & 63;
    const int wv   = tid >> 6;
    const int myslot = lane & (KBLK - 1);

    const float* XA = pts + (size_t)(bA * 3 + 0) * NPTS;
    const float* YA = pts + (size_t)(bA * 3 + 1) * NPTS;
    const float* ZA = pts + (size_t)(bA * 3 + 2) * NPTS;
    const float* XB = pts + (size_t)(bB * 3 + 0) * NPTS;
    const float* YB = pts + (size_t)(bB * 3 + 1) * NPTS;
    const float* ZB = pts + (size_t)(bB * 3 + 2) * NPTS;
    float* outA = out + (size_t)bA * 3 * S;
    float* outB = out + (size_t)bB * 3 * S;

    const int base = blk * CHUNK + tid;    // owned: base + k*TPB, k<PPT

    float pxA[PPT], pyA[PPT], pzA[PPT], mdA[PPT];
    float pxB[PPT], pyB[PPT], pzB[PPT], mdB[PPT];
#pragma unroll
    for (int k = 0; k < PPT; ++k) {
        int gi = base + k * TPB;
        pxA[k] = XA[gi]; pyA[k] = YA[gi]; pzA[k] = ZA[gi]; mdA[k] = 1e10f;
        pxB[k] = XB[gi]; pyB[k] = YB[gi]; pzB[k] = ZB[gi]; mdB[k] = 1e10f;
    }

    __shared__ unsigned long long s_pA[NWAVE];
    __shared__ unsigned long long s_pB[NWAVE];

    // Slot arrays (parity-free tags make reuse safe; keep 2 parities anyway
    // to decouple A-phase stores from B-phase stores on distinct lines).
    unsigned long long* const slotsA0 = part + (size_t)bA * KBLK;
    unsigned long long* const slotsA1 = part + (size_t)(BATCHES + bA) * KBLK;
    unsigned long long* const slotsB0 = part + (size_t)bB * KBLK;
    unsigned long long* const slotsB1 = part + (size_t)(BATCHES + bB) * KBLK;

    // Round 0 selection is index 0 (reference).
    float cxA = XA[0], cyA = YA[0], czA = ZA[0];
    float cxB = XB[0], cyB = YB[0], czB = ZB[0];
    if (blk == 0 && tid == 0) {
        outA[0] = cxA; outA[(size_t)S] = cyA; outA[(size_t)2 * S] = czA;
        outB[0] = cxB; outB[(size_t)S] = cyB; outB[(size_t)2 * S] = czB;
    }

    for (int t = 0; t < S - 1; ++t) {
        const unsigned long long tag = (unsigned long long)(t + 1); // 1..2047
        unsigned long long* slotsA = (t & 1) ? slotsA1 : slotsA0;
        unsigned long long* slotsB = (t & 1) ? slotsB1 : slotsB0;

        // Phase A: update+reduce+post (tid0 posts while others start B)
        PHASE(pxA, pyA, pzA, mdA, cxA, cyA, czA, s_pA, slotsA);
        // Phase B
        PHASE(pxB, pyB, pzB, mdB, cxB, cyB, czB, s_pB, slotsB);

        // Poll A (posted ~1 phase ago — usually ready on first read)
        unsigned long long gA;
        POLL(slotsA, gA);
        int farA = 0x1FFFF - (int)((gA >> 12) & 0x1FFFF);
        farA = __builtin_amdgcn_readfirstlane(farA);
        cxA = XA[farA]; cyA = YA[farA]; czA = ZA[farA];
        if (blk == 0 && tid == 0) {
            outA[(size_t)(t + 1)]         = cxA;
            outA[(size_t)S + (t + 1)]     = cyA;
            outA[(size_t)2 * S + (t + 1)] = czA;
        }

        // Poll B (aged further behind A's tail work)
        unsigned long long gB;
        POLL(slotsB, gB);
        int farB = 0x1FFFF - (int)((gB >> 12) & 0x1FFFF);
        farB = __builtin_amdgcn_readfirstlane(farB);
        cxB = XB[farB]; cyB = YB[farB]; czB = ZB[farB];
        if (blk == 0 && tid == 0) {
            outB[(size_t)(t + 1)]         = cxB;
            outB[(size_t)S + (t + 1)]     = cyB;
            outB[(size_t)2 * S + (t + 1)] = czB;
        }
    }
}

extern "C" void kernel_launch(void* const* d_in, const int* in_sizes, int n_in,
                              void* d_out, int out_size, void* d_ws, size_t ws_size,
                              hipStream_t stream) {
    const float* pts = (const float*)d_in[0];
    float* out = (float*)d_out;
    unsigned long long* part = (unsigned long long*)d_ws;
    int S = out_size / (BATCHES * 3);   // 2048

    // Reset sync slots every replay (captured in the graph).
    hipMemsetAsync(d_ws, 0,
                   (size_t)2 * BATCHES * KBLK * sizeof(unsigned long long),
                   stream);

    void* args[] = { (void*)&pts, (void*)&out, (void*)&part, (void*)&S };
    hipLaunchCooperativeKernel((const void*)fps_kernel,
                               dim3(NPAIR * KBLK), dim3(TPB),
                               args, 0, stream);
}

// Round 6
// 4982.395 us; speedup vs baseline: 1.1672x; 1.1656x over previous
//
#include <hip/hip_runtime.h>
#include <stdint.h>

// FPS: B=8, C=3, N=131072, S=2048.
// R3-proven shape: 16 blocks x 256 threads per batch (128 blocks, cooperative).
// batch = blockIdx % 8 -> co-XCD placement heuristic (L2 locality only).
// CONTIGUOUS ownership: thread owns 32 consecutive point indices, so
// idx order == lane order == wave order == block order, and all argmax
// tie-breaks reduce to "first participant achieving the max" (exact
// jnp.argmax first-occurrence semantics).
// Per round: register update (exact __f*_rn arithmetic) -> 32-bit fmax
// shfl butterfly + ballot/ffs (ties -> lowest lane = lowest index) ->
// parity LDS exchange (ONE barrier) -> leader posts packed u64 slot
// (agent scope, IC-coherent) -> poll 16 slots -> 4-step u64 butterfly ->
// far -> scalar gather (L2-hot) -> emit.
// Packed: (valbits<<32) | ((0x1FFFF-idx)<<12) | tag ; u64 max ==
// (value desc, index asc). Trajectory bitwise-identical to reference
// (absmax 0 in rounds 1-5).

#define BATCHES 8
#define NPTS    131072
#define KBLK    16
#define TPB     256
#define NWAVE   (TPB / 64)
#define CHUNK   (NPTS / KBLK)   // 8192
#define PPT     (CHUNK / TPB)   // 32

__global__ __launch_bounds__(TPB) void fps_kernel(
    const float* __restrict__ pts, float* __restrict__ out,
    unsigned long long* __restrict__ part, int S)
{
    const int gb   = blockIdx.x;
    const int b    = gb & (BATCHES - 1);   // batch (co-XCD heuristic)
    const int blk  = gb >> 3;              // 0..15 within batch
    const int tid  = threadIdx.x;
    const int lane = tid & 63;
    const int wv   = tid >> 6;
    const int myslot = lane & (KBLK - 1);

    const float* X = pts + (size_t)(b * 3 + 0) * NPTS;
    const float* Y = pts + (size_t)(b * 3 + 1) * NPTS;
    const float* Z = pts + (size_t)(b * 3 + 2) * NPTS;
    float* outb = out + (size_t)b * 3 * S;

    // Contiguous ownership: [base2, base2+PPT)
    const int base2 = blk * CHUNK + tid * PPT;

    float px[PPT], py[PPT], pz[PPT], md[PPT];
#pragma unroll
    for (int q = 0; q < PPT / 4; ++q) {
        float4 vx = *reinterpret_cast<const float4*>(&X[base2 + 4 * q]);
        float4 vy = *reinterpret_cast<const float4*>(&Y[base2 + 4 * q]);
        float4 vz = *reinterpret_cast<const float4*>(&Z[base2 + 4 * q]);
        px[4*q+0] = vx.x; px[4*q+1] = vx.y; px[4*q+2] = vx.z; px[4*q+3] = vx.w;
        py[4*q+0] = vy.x; py[4*q+1] = vy.y; py[4*q+2] = vy.z; py[4*q+3] = vy.w;
        pz[4*q+0] = vz.x; pz[4*q+1] = vz.y; pz[4*q+2] = vz.z; pz[4*q+3] = vz.w;
    }
#pragma unroll
    for (int k = 0; k < PPT; ++k) md[k] = 1e10f;

    __shared__ unsigned long long s_part[2][NWAVE];

    unsigned long long* const slotsA = part + (size_t)b * KBLK;
    unsigned long long* const slotsB = part + (size_t)(BATCHES + b) * KBLK;

    // Round 0 selection is index 0 (reference).
    float cx = X[0], cy = Y[0], cz = Z[0];
    if (blk == 0 && tid == 0) {
        outb[0]             = cx;
        outb[(size_t)S]     = cy;
        outb[(size_t)2 * S] = cz;
    }

    for (int t = 0; t < S - 1; ++t) {
        // --- update min-dist + thread-local argmax (ascending k, strict >) ---
        float bv = -1.0f;
        int   bk = 0;
#pragma unroll
        for (int k = 0; k < PPT; ++k) {
            float dx = __fsub_rn(px[k], cx);
            float dy = __fsub_rn(py[k], cy);
            float dz = __fsub_rn(pz[k], cz);
            // numpy/jax order: (dx*dx + dy*dy) + dz*dz, no FMA contraction
            float d  = __fadd_rn(__fadd_rn(__fmul_rn(dx, dx), __fmul_rn(dy, dy)),
                                 __fmul_rn(dz, dz));
            float m  = fminf(md[k], d);
            md[k] = m;
            if (m > bv) { bv = m; bk = k; }
        }
        const int bi = base2 + bk;   // global index of thread winner

        // --- wave reduce: 32-bit fmax butterfly; tie -> lowest lane (==
        //     lowest index, by contiguous ownership) via ballot/ffs ---
        float v = bv;
#pragma unroll
        for (int off = 32; off >= 1; off >>= 1)
            v = fmaxf(v, __shfl_xor(v, off));
        unsigned long long eq = __ballot(bv == v);
        int flane = __ffsll(eq) - 1;
        int widx  = __shfl(bi, flane);

        // --- cross-wave exchange: parity slot -> ONE barrier per round ---
        const int par = t & 1;
        if (lane == 0)
            s_part[par][wv] =
                ((unsigned long long)__float_as_uint(v) << 32) |
                ((unsigned long long)(unsigned)(0x1FFFF - widx) << 12);
        __syncthreads();
        unsigned long long bp = s_part[par][0];
#pragma unroll
        for (int w = 1; w < NWAVE; ++w) {
            unsigned long long o = s_part[par][w];
            if (o > bp) bp = o;
        }

        // --- post block partial (packed u64 + 12-bit round tag) ---
        const unsigned long long tag = (unsigned long long)(t + 1); // 1..2047
        unsigned long long* slots = par ? slotsB : slotsA;
        if (tid == 0)
            __hip_atomic_store(&slots[blk], bp | tag,
                               __ATOMIC_RELAXED, __HIP_MEMORY_SCOPE_AGENT);

        // --- poll the batch's 16 slots (2 cachelines, lane-parallel) ---
        unsigned long long got;
        for (;;) {
            got = __hip_atomic_load(&slots[myslot],
                                    __ATOMIC_RELAXED, __HIP_MEMORY_SCOPE_AGENT);
            if (__all((int)((got & 0xFFFull) == tag))) break;
        }

        // --- max over the 16 partials (4-step u64 butterfly), uniform ---
#pragma unroll
        for (int off = 8; off >= 1; off >>= 1) {
            unsigned long long o = __shfl_xor(got, off);
            if (o > got) got = o;
        }
        int far = 0x1FFFF - (int)((got >> 12) & 0x1FFFF);
        far = __builtin_amdgcn_readfirstlane(far);

        // --- next center (uniform scalar loads, L2-hot) + emit output ---
        cx = X[far]; cy = Y[far]; cz = Z[far];
        if (blk == 0 && tid == 0) {
            outb[(size_t)(t + 1)]         = cx;
            outb[(size_t)S + (t + 1)]     = cy;
            outb[(size_t)2 * S + (t + 1)] = cz;
        }
    }
}

extern "C" void kernel_launch(void* const* d_in, const int* in_sizes, int n_in,
                              void* d_out, int out_size, void* d_ws, size_t ws_size,
                              hipStream_t stream) {
    const float* pts = (const float*)d_in[0];
    float* out = (float*)d_out;
    unsigned long long* part = (unsigned long long*)d_ws;
    int S = out_size / (BATCHES * 3);   // 2048

    // Reset sync slots every replay (captured in the graph).
    hipMemsetAsync(d_ws, 0,
                   (size_t)2 * BATCHES * KBLK * sizeof(unsigned long long),
                   stream);

    void* args[] = { (void*)&pts, (void*)&out, (void*)&part, (void*)&S };
    hipLaunchCooperativeKernel((const void*)fps_kernel,
                               dim3(BATCHES * KBLK), dim3(TPB),
                               args, 0, stream);
}

// Round 7
// 3915.310 us; speedup vs baseline: 1.4853x; 1.2725x over previous
//
#include <hip/hip_runtime.h>
#include <stdint.h>

// FPS: B=8, C=3, N=131072, S=2048.
// 64 blocks x 64 threads (1 wave) per batch; 512 blocks total, cooperative.
// batch = blockIdx % 8 -> co-XCD placement heuristic. Sync slots are polled
// with plain volatile (sc0) loads that are served by the XCD-local L2
// (~150-250 cy round trip) instead of agent-scope (sc1, IC, ~1400 cy).
// Correctness does NOT depend on the heuristic: tag+value share one aligned
// 8B atom; if a slot doesn't appear within CAP spins, the block posts its
// partial to a second agent-scope (IC-coherent) array and polling accepts
// either source. Visibility is XCD-symmetric, so every block whose value is
// needed remotely itself CAPs and publishes -> no hang, graceful degrade.
// Contiguous ownership (thread owns 32 consecutive indices; block owns a
// contiguous 2048-range; slot order == block order == index order) makes all
// argmax tie-breaks "lowest lane wins" == jnp.argmax first-occurrence.
// Exact __f*_rn arithmetic, (dx*dx+dy*dy)+dz*dz order: trajectory bitwise-
// identical to reference (absmax 0 in rounds 1-6).

#define BATCHES 8
#define NPTS    131072
#define KBLK    64                  // blocks per batch == slots == lanes
#define TPB     64
#define CHUNK   (NPTS / KBLK)       // 2048 points per block
#define PPT     (CHUNK / TPB)       // 32 points per thread
#define CAP     64                  // fast-poll spins before agent fallback

__global__ __launch_bounds__(TPB) void fps_kernel(
    const float* __restrict__ pts, float* __restrict__ out,
    unsigned long long* __restrict__ ws, int S)
{
    const int gb   = blockIdx.x;            // 0..511
    const int b    = gb & (BATCHES - 1);    // batch (co-XCD heuristic)
    const int blk  = gb >> 3;               // 0..63 within batch
    const int lane = threadIdx.x;           // 0..63

    const float* X = pts + (size_t)(b * 3 + 0) * NPTS;
    const float* Y = pts + (size_t)(b * 3 + 1) * NPTS;
    const float* Z = pts + (size_t)(b * 3 + 2) * NPTS;
    float* outb = out + (size_t)b * 3 * S;

    // Contiguous ownership: [base2, base2 + PPT)
    const int base2 = blk * CHUNK + lane * PPT;

    float px[PPT], py[PPT], pz[PPT], md[PPT];
#pragma unroll
    for (int q = 0; q < PPT / 4; ++q) {
        float4 vx = *reinterpret_cast<const float4*>(&X[base2 + 4 * q]);
        float4 vy = *reinterpret_cast<const float4*>(&Y[base2 + 4 * q]);
        float4 vz = *reinterpret_cast<const float4*>(&Z[base2 + 4 * q]);
        px[4*q+0] = vx.x; px[4*q+1] = vx.y; px[4*q+2] = vx.z; px[4*q+3] = vx.w;
        py[4*q+0] = vy.x; py[4*q+1] = vy.y; py[4*q+2] = vy.z; py[4*q+3] = vy.w;
        pz[4*q+0] = vz.x; pz[4*q+1] = vz.y; pz[4*q+2] = vz.z; pz[4*q+3] = vz.w;
    }
#pragma unroll
    for (int k = 0; k < PPT; ++k) md[k] = 1e10f;

    // Slot arrays: [parity][batch][KBLK]; agent (IC) backstop + fast (L2).
    unsigned long long* const agnP[2] = {
        ws + (size_t)b * KBLK,
        ws + (size_t)(BATCHES + b) * KBLK };
    volatile unsigned long long* const fstP[2] = {
        (volatile unsigned long long*)(ws + (size_t)(2 * BATCHES + b) * KBLK),
        (volatile unsigned long long*)(ws + (size_t)(3 * BATCHES + b) * KBLK) };

    // Round 0 selection is index 0 (reference).
    float cx = X[0], cy = Y[0], cz = Z[0];
    if (blk == 0 && lane == 0) {
        outb[0]             = cx;
        outb[(size_t)S]     = cy;
        outb[(size_t)2 * S] = cz;
    }

    for (int t = 0; t < S - 1; ++t) {
        // --- update min-dist + thread-local argmax (ascending k, strict >) ---
        float bv = -1.0f;
        int   bk = 0;
#pragma unroll
        for (int k = 0; k < PPT; ++k) {
            float dx = __fsub_rn(px[k], cx);
            float dy = __fsub_rn(py[k], cy);
            float dz = __fsub_rn(pz[k], cz);
            // numpy/jax order: (dx*dx + dy*dy) + dz*dz, no FMA contraction
            float d  = __fadd_rn(__fadd_rn(__fmul_rn(dx, dx), __fmul_rn(dy, dy)),
                                 __fmul_rn(dz, dz));
            float m  = fminf(md[k], d);
            md[k] = m;
            if (m > bv) { bv = m; bk = k; }
        }
        const int bi = base2 + bk;

        // --- wave reduce: fmax butterfly; tie -> lowest lane == lowest idx ---
        float v = bv;
#pragma unroll
        for (int off = 32; off >= 1; off >>= 1)
            v = fmaxf(v, __shfl_xor(v, off));
        unsigned long long eq = __ballot(bv == v);
        int   flane = __ffsll((unsigned long long)eq) - 1;
        int   widx  = __shfl(bi, flane);

        const unsigned long long tagv = (unsigned long long)(t + 1); // 1..2047
        const unsigned long long mypk =
            ((unsigned long long)__float_as_uint(v) << 32) |
            ((unsigned long long)(unsigned)(0x1FFFF - widx) << 12) | tagv;

        volatile unsigned long long* fst = fstP[t & 1];
        unsigned long long*          agn = agnP[t & 1];

        // --- post (fast, XCD-L2) ---
        if (lane == 0) fst[blk] = mypk;

        // --- poll: lane i watches slot i; agent fallback after CAP spins ---
        unsigned long long g;
        {
            int  spins  = 0;
            bool capped = false;
            for (;;) {
                unsigned long long gf = fst[lane];
                bool ok = ((gf & 0xFFFull) == tagv);
                if (capped && !ok) {
                    unsigned long long ga = __hip_atomic_load(&agn[lane],
                        __ATOMIC_RELAXED, __HIP_MEMORY_SCOPE_AGENT);
                    if ((ga & 0xFFFull) == tagv) { gf = ga; ok = true; }
                }
                g = gf;
                if (__all((int)ok)) break;
                if (!capped && ++spins == CAP) {
                    capped = true;
                    if (lane == 0)
                        __hip_atomic_store(&agn[blk], mypk,
                            __ATOMIC_RELAXED, __HIP_MEMORY_SCOPE_AGENT);
                }
            }
        }

        // --- reduce 64 slot values: fmax butterfly + ballot; slot order ==
        //     block order == index order -> lowest lane = first occurrence ---
        float gv = __uint_as_float((unsigned)(g >> 32));
        float m2 = gv;
#pragma unroll
        for (int off = 32; off >= 1; off >>= 1)
            m2 = fmaxf(m2, __shfl_xor(m2, off));
        unsigned long long eq2 = __ballot(gv == m2);
        int fl = __ffsll((unsigned long long)eq2) - 1;
        unsigned long long win = __shfl(g, fl);

        int far = 0x1FFFF - (int)((win >> 12) & 0x1FFFF);
        far = __builtin_amdgcn_readfirstlane(far);

        // --- next center (uniform scalar loads, L2-hot) + emit ---
        cx = X[far]; cy = Y[far]; cz = Z[far];
        if (blk == 0 && lane == 0) {
            outb[(size_t)(t + 1)]         = cx;
            outb[(size_t)S + (t + 1)]     = cy;
            outb[(size_t)2 * S + (t + 1)] = cz;
        }
    }
}

extern "C" void kernel_launch(void* const* d_in, const int* in_sizes, int n_in,
                              void* d_out, int out_size, void* d_ws, size_t ws_size,
                              hipStream_t stream) {
    const float* pts = (const float*)d_in[0];
    float* out = (float*)d_out;
    unsigned long long* ws = (unsigned long long*)d_ws;
    int S = out_size / (BATCHES * 3);   // 2048

    // Zero all 4 slot arrays (2 parities x {agent, fast}) every replay.
    hipMemsetAsync(d_ws, 0,
                   (size_t)4 * BATCHES * KBLK * sizeof(unsigned long long),
                   stream);

    void* args[] = { (void*)&pts, (void*)&out, (void*)&ws, (void*)&S };
    hipLaunchCooperativeKernel((const void*)fps_kernel,
                               dim3(BATCHES * KBLK), dim3(TPB),
                               args, 0, stream);
}